// Round 13
// baseline (365.528 us; speedup 1.0000x reference)
//
#include <hip/hip_runtime.h>
#include <math.h>

#define N_NODES 50000
#define N_EDGES 800000
#define D 256
#define K2 512        // concat [mean | x] feature dim
#define M_PAD 50048   // 782 * 64 rows (GEMM padding)
#define BM 64
#define BN 256
#define BK 32
#define SCAN_B 196    // ceil(N_NODES/256)
#define SPX_B 6250    // N_NODES*32/256 (8 floats per thread)
#define SPB_B 128     // 256*128/256
#define CNT_B 3125    // N_EDGES/256
#define DRAIN_F4 (32u * 1024u * 1024u / 16u)   // 32 MB in float4s

typedef __attribute__((ext_vector_type(8))) short short8;
typedef __attribute__((ext_vector_type(8))) unsigned short ushort8;
typedef __attribute__((ext_vector_type(4))) float floatx4;

#if defined(__has_builtin)
#if __has_builtin(__builtin_amdgcn_cvt_pk_f32_fp8) && __has_builtin(__builtin_amdgcn_cvt_pk_fp8_f32)
#define HAVE_HW_FP8 1
#endif
#endif
#ifndef HAVE_HW_FP8
#define HAVE_HW_FP8 0
#endif

__device__ __forceinline__ unsigned short bf16_rn(float f) {
    union { float f; unsigned u; } a; a.f = f;
    unsigned r = a.u + 0x7FFF + ((a.u >> 16) & 1);
    return (unsigned short)(r >> 16);
}
__device__ __forceinline__ float bf16_to_f(unsigned short h) {
    union { unsigned u; float f; } a; a.u = ((unsigned)h) << 16;
    return a.f;
}
__device__ __forceinline__ void load_lds16(const void* g, void* lds) {
    __builtin_amdgcn_global_load_lds((const __attribute__((address_space(1))) void*)g,
                                     (__attribute__((address_space(3))) void*)lds, 16, 0, 0);
}

// ---- fp8 e4m3 helpers ----
#if HAVE_HW_FP8
#define FP8_ACC_SCALE 1.0f
__device__ __forceinline__ unsigned int fp8x4_enc(float4 v) {
    int p = 0;
    p = __builtin_amdgcn_cvt_pk_fp8_f32(v.x, v.y, p, 0);
    p = __builtin_amdgcn_cvt_pk_fp8_f32(v.z, v.w, p, 1);
    return (unsigned int)p;
}
__device__ __forceinline__ void fp8x4_acc(unsigned int w, float* acc) {
    auto p0 = __builtin_amdgcn_cvt_pk_f32_fp8((int)w, 0);
    auto p1 = __builtin_amdgcn_cvt_pk_f32_fp8((int)w, 1);
    acc[0] += p0[0]; acc[1] += p0[1]; acc[2] += p1[0]; acc[3] += p1[1];
}
#else
#define FP8_ACC_SCALE 0x1p120f
__device__ __forceinline__ unsigned char fp8_enc1(float f) {
    union { float f; unsigned u; } a; a.f = f;
    unsigned s = (a.u >> 24) & 0x80;
    int e = (int)((a.u >> 23) & 0xFF);
    unsigned m = a.u & 0x7FFFFF;
    unsigned mr = m + 0x7FFFF + ((m >> 20) & 1);
    if (mr >= 0x800000) { mr = 0; e += 1; }
    int e8 = e - 120;
    if (e8 <= 0) return (unsigned char)s;   // FTZ
    if (e8 > 15) { e8 = 15; mr = 6u << 20; } // clamp, avoid NaN code
    unsigned char r = (unsigned char)(s | (e8 << 3) | (mr >> 20));
    if ((r & 0x7F) == 0x7F) r -= 1;
    return r;
}
__device__ __forceinline__ unsigned int fp8x4_enc(float4 v) {
    return (unsigned)fp8_enc1(v.x) | ((unsigned)fp8_enc1(v.y) << 8) |
           ((unsigned)fp8_enc1(v.z) << 16) | ((unsigned)fp8_enc1(v.w) << 24);
}
// decode-as-scaled: as_float(((b&0x80)<<24)|((b&0x7F)<<20)) == true_value * 2^-120
__device__ __forceinline__ void fp8x4_acc(unsigned int w, float* acc) {
    #pragma unroll
    for (int k = 0; k < 4; k++) {
        unsigned b = (w >> (8 * k)) & 0xFF;
        union { unsigned u; float f; } a;
        a.u = ((b & 0x80) << 24) | ((b & 0x7F) << 20);
        acc[k] += a.f;
    }
}
#endif

// ---------------- fused init: splitX (hi + fp8 only) | splitB | degree count ----------------
__global__ __launch_bounds__(256) void k_init(const float* __restrict__ x,
                                              const float* __restrict__ Wl,
                                              const float* __restrict__ Wr,
                                              const int* __restrict__ dst,
                                              unsigned short* __restrict__ Ahi,
                                              unsigned short* __restrict__ Bhi,
                                              unsigned short* __restrict__ Blo,
                                              unsigned char* __restrict__ Xf8,
                                              int* __restrict__ deg) {
    int b = blockIdx.x;
    if (b < SPX_B) {
        int t = b * 256 + threadIdx.x;            // over N*32, 8 floats each
        int m = t >> 5, j = (t & 31) * 8;
        float4 v0 = *(const float4*)&x[(size_t)m * D + j];
        float4 v1 = *(const float4*)&x[(size_t)m * D + j + 4];
        ushort8 hi;
        hi[0] = bf16_rn(v0.x); hi[1] = bf16_rn(v0.y);
        hi[2] = bf16_rn(v0.z); hi[3] = bf16_rn(v0.w);
        hi[4] = bf16_rn(v1.x); hi[5] = bf16_rn(v1.y);
        hi[6] = bf16_rn(v1.z); hi[7] = bf16_rn(v1.w);
        *(ushort8*)&Ahi[(size_t)m * K2 + 256 + j] = hi;
        uint2 f8;
        f8.x = fp8x4_enc(v0);
        f8.y = fp8x4_enc(v1);
        *(uint2*)&Xf8[(size_t)m * D + j] = f8;
    } else if (b < SPX_B + SPB_B) {
        int t = (b - SPX_B) * 256 + threadIdx.x;  // over 256*128
        int n = t >> 7, k = (t & 127) * 4;
        const float* srcp = (k < 256) ? &Wl[(size_t)n * 256 + k] : &Wr[(size_t)n * 256 + k - 256];
        float4 v = *(const float4*)srcp;
        ushort4 hi, lo;
        hi.x = bf16_rn(v.x); lo.x = bf16_rn(v.x - bf16_to_f(hi.x));
        hi.y = bf16_rn(v.y); lo.y = bf16_rn(v.y - bf16_to_f(hi.y));
        hi.z = bf16_rn(v.z); lo.z = bf16_rn(v.z - bf16_to_f(hi.z));
        hi.w = bf16_rn(v.w); lo.w = bf16_rn(v.w - bf16_to_f(hi.w));
        *(ushort4*)&Bhi[(size_t)n * K2 + k] = hi;
        *(ushort4*)&Blo[(size_t)n * K2 + k] = lo;
    } else {
        int e = (b - SPX_B - SPB_B) * 256 + threadIdx.x;
        if (e < N_EDGES) atomicAdd(&deg[dst[e]], 1);
    }
}

// ---------------- per-block degree sums ----------------
__global__ void k_scan1(const int* __restrict__ deg, int* __restrict__ bsum) {
    __shared__ int red[256];
    int b = blockIdx.x, t = threadIdx.x;
    int i = b * 256 + t;
    red[t] = (i < N_NODES) ? deg[i] : 0;
    __syncthreads();
    for (int o = 128; o; o >>= 1) {
        if (t < o) red[t] += red[t + o];
        __syncthreads();
    }
    if (t == 0) bsum[b] = red[0];
}

// ---------------- fused scan2+scan3 ----------------
__global__ void k_scan23(const int* __restrict__ deg, const int* __restrict__ bsum,
                         int* __restrict__ cursor) {
    __shared__ int sh[256];
    int b = blockIdx.x, t = threadIdx.x;
    sh[t] = (t < SCAN_B) ? bsum[t] : 0;
    __syncthreads();
    for (int o = 1; o < 256; o <<= 1) {
        int v = (t >= o) ? sh[t - o] : 0;
        __syncthreads();
        sh[t] += v;
        __syncthreads();
    }
    int boff = (b == 0) ? 0 : sh[b - 1];
    __syncthreads();
    int i = b * 256 + t;
    int v = (i < N_NODES) ? deg[i] : 0;
    sh[t] = v;
    __syncthreads();
    for (int o = 1; o < 256; o <<= 1) {
        int val = (t >= o) ? sh[t - o] : 0;
        __syncthreads();
        sh[t] += val;
        __syncthreads();
    }
    if (i < N_NODES) cursor[i] = boff + sh[t] - v;
}

// after this, cursor[i] == row END; start = cursor[i]-deg[i]
__global__ void k_bucket(const int* __restrict__ src, const int* __restrict__ dst,
                         int* __restrict__ cursor, int* __restrict__ csr_src) {
    int e = blockIdx.x * blockDim.x + threadIdx.x;
    if (e >= N_EDGES) return;
    int pos = atomicAdd(&cursor[dst[e]], 1);
    csr_src[pos] = src[e];
}

// ---------------- mean aggregation: fp8 gather, hi-only mean output ----------------
__global__ __launch_bounds__(256) void k_agg(const int* __restrict__ cursor,
                                             const int* __restrict__ deg,
                                             const int* __restrict__ csr,
                                             const unsigned char* __restrict__ Xf8,
                                             unsigned short* __restrict__ Ahi) {
    int node = blockIdx.x * 4 + (threadIdx.x >> 6);
    int lane = threadIdx.x & 63;
    if (node >= N_NODES) return;
    int d = deg[node], end = cursor[node], start = end - d;
    int h = lane >> 5;
    int col = (lane & 31) * 8;
    const unsigned char* Xb = Xf8 + col;
    float acc0[8] = {}, acc1[8] = {}, acc2[8] = {}, acc3[8] = {};
    int j = start;
    for (; j + 16 <= end; j += 16) {
        int i0 = csr[j + h],      i1 = csr[j + 2 + h],  i2 = csr[j + 4 + h],  i3 = csr[j + 6 + h];
        int i4 = csr[j + 8 + h],  i5 = csr[j + 10 + h], i6 = csr[j + 12 + h], i7 = csr[j + 14 + h];
        uint2 v0 = *(const uint2*)&Xb[(size_t)i0 * D];
        uint2 v1 = *(const uint2*)&Xb[(size_t)i1 * D];
        uint2 v2 = *(const uint2*)&Xb[(size_t)i2 * D];
        uint2 v3 = *(const uint2*)&Xb[(size_t)i3 * D];
        uint2 v4 = *(const uint2*)&Xb[(size_t)i4 * D];
        uint2 v5 = *(const uint2*)&Xb[(size_t)i5 * D];
        uint2 v6 = *(const uint2*)&Xb[(size_t)i6 * D];
        uint2 v7 = *(const uint2*)&Xb[(size_t)i7 * D];
        fp8x4_acc(v0.x, acc0); fp8x4_acc(v0.y, acc0 + 4);
        fp8x4_acc(v1.x, acc1); fp8x4_acc(v1.y, acc1 + 4);
        fp8x4_acc(v2.x, acc2); fp8x4_acc(v2.y, acc2 + 4);
        fp8x4_acc(v3.x, acc3); fp8x4_acc(v3.y, acc3 + 4);
        fp8x4_acc(v4.x, acc0); fp8x4_acc(v4.y, acc0 + 4);
        fp8x4_acc(v5.x, acc1); fp8x4_acc(v5.y, acc1 + 4);
        fp8x4_acc(v6.x, acc2); fp8x4_acc(v6.y, acc2 + 4);
        fp8x4_acc(v7.x, acc3); fp8x4_acc(v7.y, acc3 + 4);
    }
    if (j + 8 <= end) {
        int i0 = csr[j + h], i1 = csr[j + 2 + h], i2 = csr[j + 4 + h], i3 = csr[j + 6 + h];
        uint2 v0 = *(const uint2*)&Xb[(size_t)i0 * D];
        uint2 v1 = *(const uint2*)&Xb[(size_t)i1 * D];
        uint2 v2 = *(const uint2*)&Xb[(size_t)i2 * D];
        uint2 v3 = *(const uint2*)&Xb[(size_t)i3 * D];
        fp8x4_acc(v0.x, acc0); fp8x4_acc(v0.y, acc0 + 4);
        fp8x4_acc(v1.x, acc1); fp8x4_acc(v1.y, acc1 + 4);
        fp8x4_acc(v2.x, acc2); fp8x4_acc(v2.y, acc2 + 4);
        fp8x4_acc(v3.x, acc3); fp8x4_acc(v3.y, acc3 + 4);
        j += 8;
    }
    if (j + 4 <= end) {
        int i0 = csr[j + h], i1 = csr[j + 2 + h];
        uint2 v0 = *(const uint2*)&Xb[(size_t)i0 * D];
        uint2 v1 = *(const uint2*)&Xb[(size_t)i1 * D];
        fp8x4_acc(v0.x, acc0); fp8x4_acc(v0.y, acc0 + 4);
        fp8x4_acc(v1.x, acc1); fp8x4_acc(v1.y, acc1 + 4);
        j += 4;
    }
    if (j + 2 <= end) {
        int i0 = csr[j + h];
        uint2 v0 = *(const uint2*)&Xb[(size_t)i0 * D];
        fp8x4_acc(v0.x, acc0); fp8x4_acc(v0.y, acc0 + 4);
        j += 2;
    }
    if (j < end && h == 0) {
        int i0 = csr[j];
        uint2 v0 = *(const uint2*)&Xb[(size_t)i0 * D];
        fp8x4_acc(v0.x, acc0); fp8x4_acc(v0.y, acc0 + 4);
    }
    float inv = FP8_ACC_SCALE / fmaxf((float)d, 1.0f);
    ushort8 hi;
    #pragma unroll
    for (int k = 0; k < 8; k++) {
        float a = (acc0[k] + acc1[k]) + (acc2[k] + acc3[k]);
        a += __shfl_xor(a, 32);
        hi[k] = bf16_rn(a * inv);
    }
    if (h == 0) {
        *(ushort8*)&Ahi[(size_t)node * K2 + col] = hi;
    }
}

// ---------------- L2 drain: cycle every L2 set so dirty Ahi/Xf8/csr lines
// write back NOW (latency-insensitive window) instead of during the GEMM ----------------
__global__ __launch_bounds__(256) void k_drain(const float4* __restrict__ p,
                                               float* __restrict__ sink) {
    unsigned i = blockIdx.x * 256 + threadIdx.x;
    unsigned stride = gridDim.x * 256;
    float acc = 0.f;
    for (; i < DRAIN_F4; i += stride) {
        float4 v = p[i];
        acc += v.x + v.y + v.z + v.w;
    }
    if (acc == 1.0e38f) sink[0] = acc;   // never taken; defeats DCE
}

// ---------------- exact fp32 h1 rows for mention + its neighbors ----------------
__global__ __launch_bounds__(256) void k_small(const int* __restrict__ mention,
                                               const int* __restrict__ deg,
                                               const int* __restrict__ cursor,
                                               const int* __restrict__ csr,
                                               const float* __restrict__ x,
                                               const float* __restrict__ W1l,
                                               const float* __restrict__ W1r,
                                               const float* __restrict__ b1,
                                               float* __restrict__ h1m) {
    int m = mention[0];
    int dm = min(deg[m], 95);
    int slot = blockIdx.x;
    if (slot > dm) return;
    int startm = cursor[m] - deg[m];
    int node = (slot == 0) ? m : csr[startm + slot - 1];
    __shared__ float smean[D], sx[D];
    int t = threadIdx.x;
    int d = deg[node], end = cursor[node], start = end - d;
    float a = 0.f;
    for (int j = start; j < end; j++) a += x[(size_t)csr[j] * D + t];
    smean[t] = a / fmaxf((float)d, 1.0f);
    sx[t] = x[(size_t)node * D + t];
    __syncthreads();
    float z = b1[t];
    const float* wl = &W1l[(size_t)t * D];
    const float* wr = &W1r[(size_t)t * D];
    for (int k = 0; k < D; k += 4) {
        float4 a4 = *(const float4*)&wl[k];
        float4 b4 = *(const float4*)&wr[k];
        z += smean[k] * a4.x + smean[k + 1] * a4.y + smean[k + 2] * a4.z + smean[k + 3] * a4.w
           + sx[k] * b4.x + sx[k + 1] * b4.y + sx[k + 2] * b4.z + sx[k + 3] * b4.w;
    }
    h1m[(size_t)slot * D + t] = fmaxf(z, 0.f);
}

// ---------------- v = h2[mention]: 16 blocks x 16 rows, 16-lane dots ----------------
__global__ __launch_bounds__(256) void k_v(const int* __restrict__ mention,
                                           const int* __restrict__ deg,
                                           const float* __restrict__ h1m,
                                           const float* __restrict__ W2l,
                                           const float* __restrict__ W2r,
                                           const float* __restrict__ b2,
                                           float* __restrict__ v) {
    __shared__ float sm[D], sh[D];
    int m = mention[0];
    int dm = min(deg[m], 95);
    int t = threadIdx.x;
    float a = 0.f;
    for (int j = 1; j <= dm; j++) a += h1m[(size_t)j * D + t];
    sm[t] = a / fmaxf((float)deg[m], 1.0f);
    sh[t] = h1m[t];
    __syncthreads();
    int o = t >> 4, p = t & 15;
    int row = blockIdx.x * 16 + o;
    const float* wl = &W2l[(size_t)row * D];
    const float* wr = &W2r[(size_t)row * D];
    float acc = 0.f;
    int k0 = p * 16;
    #pragma unroll
    for (int k = k0; k < k0 + 16; k += 4) {
        float4 a4 = *(const float4*)&wl[k];
        float4 b4 = *(const float4*)&wr[k];
        acc += sm[k] * a4.x + sm[k + 1] * a4.y + sm[k + 2] * a4.z + sm[k + 3] * a4.w
             + sh[k] * b4.x + sh[k + 1] * b4.y + sh[k + 2] * b4.z + sh[k + 3] * b4.w;
    }
    #pragma unroll
    for (int off = 1; off < 16; off <<= 1) acc += __shfl_xor(acc, off);
    if (p == 0) v[row] = acc + b2[row];
}

// ---------------- u = [W2l^T v ; W2r^T v]; c = b2 . v ----------------
__global__ __launch_bounds__(256) void k_u(const float* __restrict__ W2l,
                                           const float* __restrict__ W2r,
                                           const float* __restrict__ b2,
                                           const float* __restrict__ v,
                                           float* __restrict__ u,
                                           float* __restrict__ cout) {
    __shared__ float sv[D];
    __shared__ float r1[4][64], r2[4][64], red[256];
    int t = threadIdx.x;
    sv[t] = v[t];
    __syncthreads();
    int lane = t & 63, p = t >> 6;
    int col = blockIdx.x * 64 + lane;
    float a1 = 0.f, a2 = 0.f;
    for (int n = p; n < D; n += 4) {
        float vv = sv[n];
        a1 += W2l[(size_t)n * D + col] * vv;
        a2 += W2r[(size_t)n * D + col] * vv;
    }
    r1[p][lane] = a1; r2[p][lane] = a2;
    __syncthreads();
    if (p == 0) {
        u[col] = r1[0][lane] + r1[1][lane] + r1[2][lane] + r1[3][lane];
        u[D + col] = r2[0][lane] + r2[1][lane] + r2[2][lane] + r2[3][lane];
    }
    if (blockIdx.x == 0) {
        red[t] = b2[t] * sv[t];
        __syncthreads();
        for (int o = 128; o; o >>= 1) {
            if (t < o) red[t] += red[t + o];
            __syncthreads();
        }
        if (t == 0) cout[0] = red[0];
    }
}

// ---------------- fused split-bf16 MFMA GEMM + relu + projection epilogue ----------------
// BM=64 x BN=256, 256 threads / 4 waves. Phase 1 (mean half): hi*hi.
// Phase 2 (x half): Ahi*(Bhi+Blo). Measured absmax 3.05e-5 (R12).
__global__ __launch_bounds__(256, 4)
void k_gemm_fused(const unsigned short* __restrict__ Ahi,
                  const unsigned short* __restrict__ Bhi,
                  const unsigned short* __restrict__ Blo,
                  const float* __restrict__ bias,
                  const float* __restrict__ u,    // u1[256] then u2[256]
                  float* __restrict__ s,
                  float* __restrict__ t_) {
    __shared__ unsigned short sA[BM * BK];      // 4 KB
    __shared__ unsigned short sB[2][BN * BK];   // 32 KB
    __shared__ float sred[BM], tred[BM];
    int tid = threadIdx.x;
    int br = blockIdx.x;
    int lane = tid & 63, wv = tid >> 6;          // 4 waves
    int wn = wv * 64;
    int q = lane >> 4, r = lane & 15;

    float biasv[4], u1v[4], u2v[4];
    #pragma unroll
    for (int nt = 0; nt < 4; nt++) {
        int gc = wn + nt * 16 + r;
        biasv[nt] = bias[gc];
        u1v[nt] = u[gc];
        u2v[nt] = u[256 + gc];
    }
    if (tid < BM) { sred[tid] = 0.f; tred[tid] = 0.f; }

    floatx4 acc[4][4] = {};

    const size_t arow0 = (size_t)br * BM;
    int seg = lane & 3;
    int rl16 = lane >> 2;

    // ---- phase 1: kt 0..7 (mean half), hi*hi ----
    for (int kt = 0; kt < 8; kt++) {
        {
            size_t gA = (arow0 + wv * 16 + rl16) * (size_t)K2 + kt * BK + seg * 8;
            load_lds16(Ahi + gA, &sA[(wv * 16) * BK]);
        }
        #pragma unroll
        for (int t = 0; t < 4; t++) {
            int rloc = wv * 64 + t * 16 + rl16;
            size_t gB = (size_t)rloc * K2 + kt * BK + seg * 8;
            load_lds16(Bhi + gB, &sB[0][(wv * 64 + t * 16) * BK]);
        }
        __syncthreads();
        short8 ah[4], bh[4];
        #pragma unroll
        for (int i = 0; i < 4; i++) {
            ah[i] = *(const short8*)&sA[(i * 16 + r) * BK + q * 8];
            bh[i] = *(const short8*)&sB[0][(wn + i * 16 + r) * BK + q * 8];
        }
        #pragma unroll
        for (int mt = 0; mt < 4; mt++)
            #pragma unroll
            for (int nt = 0; nt < 4; nt++)
                acc[mt][nt] = __builtin_amdgcn_mfma_f32_16x16x32_bf16(ah[mt], bh[nt], acc[mt][nt], 0, 0, 0);
        __syncthreads();
    }

    // ---- phase 2: kt 8..15 (x half), Ahi*(Bhi+Blo) ----
    for (int kt = 8; kt < 16; kt++) {
        {
            size_t gA = (arow0 + wv * 16 + rl16) * (size_t)K2 + kt * BK + seg * 8;
            load_lds16(Ahi + gA, &sA[(wv * 16) * BK]);
        }
        #pragma unroll
        for (int t = 0; t < 4; t++) {
            int rloc = wv * 64 + t * 16 + rl16;
            size_t gB = (size_t)rloc * K2 + kt * BK + seg * 8;
            load_lds16(Bhi + gB, &sB[0][(wv * 64 + t * 16) * BK]);
            load_lds16(Blo + gB, &sB[1][(wv * 64 + t * 16) * BK]);
        }
        __syncthreads();
        short8 ah[4], bh[4], bl[4];
        #pragma unroll
        for (int i = 0; i < 4; i++) {
            ah[i] = *(const short8*)&sA[(i * 16 + r) * BK + q * 8];
            bh[i] = *(const short8*)&sB[0][(wn + i * 16 + r) * BK + q * 8];
            bl[i] = *(const short8*)&sB[1][(wn + i * 16 + r) * BK + q * 8];
        }
        #pragma unroll
        for (int mt = 0; mt < 4; mt++)
            #pragma unroll
            for (int nt = 0; nt < 4; nt++) {
                acc[mt][nt] = __builtin_amdgcn_mfma_f32_16x16x32_bf16(ah[mt], bh[nt], acc[mt][nt], 0, 0, 0);
                acc[mt][nt] = __builtin_amdgcn_mfma_f32_16x16x32_bf16(ah[mt], bl[nt], acc[mt][nt], 0, 0, 0);
            }
        __syncthreads();
    }

    #pragma unroll
    for (int mt = 0; mt < 4; mt++) {
        #pragma unroll
        for (int reg = 0; reg < 4; reg++) {
            float sacc = 0.f, tacc = 0.f;
            #pragma unroll
            for (int nt = 0; nt < 4; nt++) {
                float h = fmaxf(acc[mt][nt][reg] + biasv[nt], 0.f);
                sacc += h * u1v[nt];
                tacc += h * u2v[nt];
            }
            #pragma unroll
            for (int off = 1; off < 16; off <<= 1) {
                sacc += __shfl_xor(sacc, off);
                tacc += __shfl_xor(tacc, off);
            }
            if (r == 0) {
                int row = mt * 16 + q * 4 + reg;
                atomicAdd(&sred[row], sacc);
                atomicAdd(&tred[row], tacc);
            }
        }
    }
    __syncthreads();
    if (tid < BM) {
        size_t grow = arow0 + tid;
        if (grow < N_NODES) {
            s[grow] = sred[tid];
            t_[grow] = tred[tid];
        }
    }
}

// ---------------- fused logits + per-block softmax partials ----------------
__global__ __launch_bounds__(256) void k_logits_sm1(const int* __restrict__ deg,
                                                    const int* __restrict__ cursor,
                                                    const int* __restrict__ csr,
                                                    const float* __restrict__ s,
                                                    const float* __restrict__ t_,
                                                    const float* __restrict__ cptr,
                                                    float* __restrict__ logits,
                                                    float* __restrict__ pmax,
                                                    float* __restrict__ psum) {
    __shared__ float red[256];
    int b = blockIdx.x, t = threadIdx.x;
    int i = b * 256 + t;
    float lg = -INFINITY;
    if (i < N_NODES) {
        int d = deg[i];
        int end = cursor[i];
        int j = end - d;
        float sum = 0.f;
        for (; j + 4 <= end; j += 4) {     // 4 independent gathers in flight
            int i0 = csr[j], i1 = csr[j + 1], i2 = csr[j + 2], i3 = csr[j + 3];
            sum += (s[i0] + s[i1]) + (s[i2] + s[i3]);
        }
        for (; j < end; j++) sum += s[csr[j]];
        lg = sum / fmaxf((float)d, 1.0f) + t_[i] + cptr[0];
        logits[i] = lg;
    }
    red[t] = lg;
    __syncthreads();
    for (int o = 128; o; o >>= 1) {
        if (t < o) red[t] = fmaxf(red[t], red[t + o]);
        __syncthreads();
    }
    float mb = red[0];
    __syncthreads();
    red[t] = (i < N_NODES) ? __expf(lg - mb) : 0.f;
    __syncthreads();
    for (int o = 128; o; o >>= 1) {
        if (t < o) red[t] += red[t + o];
        __syncthreads();
    }
    if (t == 0) { pmax[b] = mb; psum[b] = red[0]; }
}

// ---------------- fused sm2+sm3: redundant partial-reduce + finalize ----------------
__global__ __launch_bounds__(256) void k_sm23(const float* __restrict__ logits,
                                              const float* __restrict__ pmax,
                                              const float* __restrict__ psum,
                                              float* __restrict__ out) {
    __shared__ float rm[256], rs[256];
    int b = blockIdx.x, t = threadIdx.x;
    float m = (t < SCAN_B) ? pmax[t] : -INFINITY;
    rm[t] = m;
    __syncthreads();
    for (int o = 128; o; o >>= 1) {
        if (t < o) rm[t] = fmaxf(rm[t], rm[t + o]);
        __syncthreads();
    }
    float g = rm[0];
    __syncthreads();
    rs[t] = (t < SCAN_B) ? psum[t] * __expf(m - g) : 0.f;
    __syncthreads();
    for (int o = 128; o; o >>= 1) {
        if (t < o) rs[t] += rs[t + o];
        __syncthreads();
    }
    float inv = 1.0f / rs[0];
    int i = b * 256 + t;
    if (i < N_NODES) out[i] = __expf(logits[i] - g) * inv;
}

extern "C" void kernel_launch(void* const* d_in, const int* in_sizes, int n_in,
                              void* d_out, int out_size, void* d_ws, size_t ws_size,
                              hipStream_t stream) {
    const float* x   = (const float*)d_in[0];
    const int*   ei  = (const int*)d_in[1];
    const int*   src = ei;
    const int*   dst = ei + N_EDGES;
    const int*   mention = (const int*)d_in[2];
    const float* W1l = (const float*)d_in[3];
    const float* b1  = (const float*)d_in[4];
    const float* W1r = (const float*)d_in[5];
    const float* W2l = (const float*)d_in[6];
    const float* b2  = (const float*)d_in[7];
    const float* W2r = (const float*)d_in[8];

    char* w = (char*)d_ws;
    unsigned short* Ahi = (unsigned short*)w;  w += (size_t)M_PAD * K2 * 2;
    unsigned short* Bhi = (unsigned short*)w;  w += (size_t)256 * K2 * 2;
    unsigned short* Blo = (unsigned short*)w;  w += (size_t)256 * K2 * 2;
    unsigned char* Xf8 = (unsigned char*)w;    w += (size_t)N_NODES * D;
    float* s     = (float*)w;  w += (size_t)N_NODES * 4;
    float* t_    = (float*)w;  w += (size_t)N_NODES * 4;
    int* deg     = (int*)w;    w += (size_t)N_NODES * 4;   // zeroed
    float* logit = (float*)w;  w += (size_t)N_NODES * 4;
    float* h1m   = (float*)w;  w += (size_t)96 * D * 4;
    float* vbuf  = (float*)w;  w += D * 4;
    float* u     = (float*)w;  w += 2 * D * 4;
    float* c     = (float*)w;  w += 16;
    float* pmax  = (float*)w;  w += 256 * 4;
    float* psum  = (float*)w;  w += 256 * 4;
    float* sink  = (float*)w;  w += 16;
    int* cursor  = (int*)w;    w += (size_t)N_NODES * 4;
    int* bsum    = (int*)w;    w += 256 * 4;
    int* csr     = (int*)w;    w += (size_t)N_EDGES * 4;
    float4* drain = (float4*)w;  // 32 MB scratch read region (poison contents OK)

    hipMemsetAsync(deg, 0, (size_t)N_NODES * sizeof(int), stream);

    k_init  <<<SPX_B + SPB_B + CNT_B, 256, 0, stream>>>(x, W1l, W1r, dst,
                                                        Ahi, Bhi, Blo, Xf8, deg);
    k_scan1 <<<SCAN_B, 256, 0, stream>>>(deg, bsum);
    k_scan23<<<SCAN_B, 256, 0, stream>>>(deg, bsum, cursor);
    k_bucket<<<(N_EDGES + 255) / 256, 256, 0, stream>>>(src, dst, cursor, csr);

    k_agg   <<<(N_NODES + 3) / 4, 256, 0, stream>>>(cursor, deg, csr, Xf8, Ahi);

    k_drain <<<1024, 256, 0, stream>>>(drain, sink);

    k_small <<<96, 256, 0, stream>>>(mention, deg, cursor, csr, x, W1l, W1r, b1, h1m);
    k_v     <<<16, 256, 0, stream>>>(mention, deg, h1m, W2l, W2r, b2, vbuf);
    k_u     <<<4, 256, 0, stream>>>(W2l, W2r, b2, vbuf, u, c);

    k_gemm_fused<<<M_PAD / BM, 256, 0, stream>>>(Ahi, Bhi, Blo, b1, u, s, t_);

    k_logits_sm1<<<SCAN_B, 256, 0, stream>>>(deg, cursor, csr, s, t_, c, logit, pmax, psum);
    k_sm23  <<<SCAN_B, 256, 0, stream>>>(logit, pmax, psum, (float*)d_out);
}

// Round 14
// 338.544 us; speedup vs baseline: 1.0797x; 1.0797x over previous
//
#include <hip/hip_runtime.h>
#include <math.h>

#define N_NODES 50000
#define N_EDGES 800000
#define D 256
#define K2 512        // concat [mean | x] feature dim
#define M_PAD 50048   // 782 * 64 rows (GEMM padding)
#define BM 64
#define BN 256
#define BK 32
#define SCAN_B 196    // ceil(N_NODES/256)
#define SPX_B 6250    // N_NODES*32/256 (8 floats per thread)
#define SPB_B 128     // 256*128/256
#define CNT_B 3125    // N_EDGES/256

typedef __attribute__((ext_vector_type(8))) short short8;
typedef __attribute__((ext_vector_type(8))) unsigned short ushort8;
typedef __attribute__((ext_vector_type(4))) float floatx4;

#if defined(__has_builtin)
#if __has_builtin(__builtin_amdgcn_cvt_pk_f32_fp8) && __has_builtin(__builtin_amdgcn_cvt_pk_fp8_f32)
#define HAVE_HW_FP8 1
#endif
#endif
#ifndef HAVE_HW_FP8
#define HAVE_HW_FP8 0
#endif

__device__ __forceinline__ unsigned short bf16_rn(float f) {
    union { float f; unsigned u; } a; a.f = f;
    unsigned r = a.u + 0x7FFF + ((a.u >> 16) & 1);
    return (unsigned short)(r >> 16);
}
__device__ __forceinline__ float bf16_to_f(unsigned short h) {
    union { unsigned u; float f; } a; a.u = ((unsigned)h) << 16;
    return a.f;
}
__device__ __forceinline__ void load_lds16(const void* g, void* lds) {
    __builtin_amdgcn_global_load_lds((const __attribute__((address_space(1))) void*)g,
                                     (__attribute__((address_space(3))) void*)lds, 16, 0, 0);
}

// ---- fp8 e4m3 helpers ----
#if HAVE_HW_FP8
#define FP8_ACC_SCALE 1.0f
__device__ __forceinline__ unsigned int fp8x4_enc(float4 v) {
    int p = 0;
    p = __builtin_amdgcn_cvt_pk_fp8_f32(v.x, v.y, p, 0);
    p = __builtin_amdgcn_cvt_pk_fp8_f32(v.z, v.w, p, 1);
    return (unsigned int)p;
}
__device__ __forceinline__ void fp8x4_acc(unsigned int w, float* acc) {
    auto p0 = __builtin_amdgcn_cvt_pk_f32_fp8((int)w, 0);
    auto p1 = __builtin_amdgcn_cvt_pk_f32_fp8((int)w, 1);
    acc[0] += p0[0]; acc[1] += p0[1]; acc[2] += p1[0]; acc[3] += p1[1];
}
#else
#define FP8_ACC_SCALE 0x1p120f
__device__ __forceinline__ unsigned char fp8_enc1(float f) {
    union { float f; unsigned u; } a; a.f = f;
    unsigned s = (a.u >> 24) & 0x80;
    int e = (int)((a.u >> 23) & 0xFF);
    unsigned m = a.u & 0x7FFFFF;
    unsigned mr = m + 0x7FFFF + ((m >> 20) & 1);
    if (mr >= 0x800000) { mr = 0; e += 1; }
    int e8 = e - 120;
    if (e8 <= 0) return (unsigned char)s;   // FTZ
    if (e8 > 15) { e8 = 15; mr = 6u << 20; } // clamp, avoid NaN code
    unsigned char r = (unsigned char)(s | (e8 << 3) | (mr >> 20));
    if ((r & 0x7F) == 0x7F) r -= 1;
    return r;
}
__device__ __forceinline__ unsigned int fp8x4_enc(float4 v) {
    return (unsigned)fp8_enc1(v.x) | ((unsigned)fp8_enc1(v.y) << 8) |
           ((unsigned)fp8_enc1(v.z) << 16) | ((unsigned)fp8_enc1(v.w) << 24);
}
// decode-as-scaled: as_float(((b&0x80)<<24)|((b&0x7F)<<20)) == true_value * 2^-120
__device__ __forceinline__ void fp8x4_acc(unsigned int w, float* acc) {
    #pragma unroll
    for (int k = 0; k < 4; k++) {
        unsigned b = (w >> (8 * k)) & 0xFF;
        union { unsigned u; float f; } a;
        a.u = ((b & 0x80) << 24) | ((b & 0x7F) << 20);
        acc[k] += a.f;
    }
}
#endif

// ---------------- fused init: splitX (hi+lo+fp8, 8 floats/thread) | splitB | count ----------------
__global__ __launch_bounds__(256) void k_init(const float* __restrict__ x,
                                              const float* __restrict__ Wl,
                                              const float* __restrict__ Wr,
                                              const int* __restrict__ dst,
                                              unsigned short* __restrict__ Ahi,
                                              unsigned short* __restrict__ Alo,
                                              unsigned short* __restrict__ Bhi,
                                              unsigned short* __restrict__ Blo,
                                              unsigned char* __restrict__ Xf8,
                                              int* __restrict__ deg) {
    int b = blockIdx.x;
    if (b < SPX_B) {
        int t = b * 256 + threadIdx.x;            // over N*32, 8 floats each
        int m = t >> 5, j = (t & 31) * 8;
        float4 v0 = *(const float4*)&x[(size_t)m * D + j];
        float4 v1 = *(const float4*)&x[(size_t)m * D + j + 4];
        ushort8 hi, lo;
        hi[0] = bf16_rn(v0.x); lo[0] = bf16_rn(v0.x - bf16_to_f(hi[0]));
        hi[1] = bf16_rn(v0.y); lo[1] = bf16_rn(v0.y - bf16_to_f(hi[1]));
        hi[2] = bf16_rn(v0.z); lo[2] = bf16_rn(v0.z - bf16_to_f(hi[2]));
        hi[3] = bf16_rn(v0.w); lo[3] = bf16_rn(v0.w - bf16_to_f(hi[3]));
        hi[4] = bf16_rn(v1.x); lo[4] = bf16_rn(v1.x - bf16_to_f(hi[4]));
        hi[5] = bf16_rn(v1.y); lo[5] = bf16_rn(v1.y - bf16_to_f(hi[5]));
        hi[6] = bf16_rn(v1.z); lo[6] = bf16_rn(v1.z - bf16_to_f(hi[6]));
        hi[7] = bf16_rn(v1.w); lo[7] = bf16_rn(v1.w - bf16_to_f(hi[7]));
        *(ushort8*)&Ahi[(size_t)m * K2 + 256 + j] = hi;
        *(ushort8*)&Alo[(size_t)m * K2 + 256 + j] = lo;
        uint2 f8;
        f8.x = fp8x4_enc(v0);
        f8.y = fp8x4_enc(v1);
        *(uint2*)&Xf8[(size_t)m * D + j] = f8;
    } else if (b < SPX_B + SPB_B) {
        int t = (b - SPX_B) * 256 + threadIdx.x;  // over 256*128
        int n = t >> 7, k = (t & 127) * 4;
        const float* srcp = (k < 256) ? &Wl[(size_t)n * 256 + k] : &Wr[(size_t)n * 256 + k - 256];
        float4 v = *(const float4*)srcp;
        ushort4 hi, lo;
        hi.x = bf16_rn(v.x); lo.x = bf16_rn(v.x - bf16_to_f(hi.x));
        hi.y = bf16_rn(v.y); lo.y = bf16_rn(v.y - bf16_to_f(hi.y));
        hi.z = bf16_rn(v.z); lo.z = bf16_rn(v.z - bf16_to_f(hi.z));
        hi.w = bf16_rn(v.w); lo.w = bf16_rn(v.w - bf16_to_f(hi.w));
        *(ushort4*)&Bhi[(size_t)n * K2 + k] = hi;
        *(ushort4*)&Blo[(size_t)n * K2 + k] = lo;
    } else {
        int e = (b - SPX_B - SPB_B) * 256 + threadIdx.x;
        if (e < N_EDGES) atomicAdd(&deg[dst[e]], 1);
    }
}

// ---------------- per-block degree sums ----------------
__global__ void k_scan1(const int* __restrict__ deg, int* __restrict__ bsum) {
    __shared__ int red[256];
    int b = blockIdx.x, t = threadIdx.x;
    int i = b * 256 + t;
    red[t] = (i < N_NODES) ? deg[i] : 0;
    __syncthreads();
    for (int o = 128; o; o >>= 1) {
        if (t < o) red[t] += red[t + o];
        __syncthreads();
    }
    if (t == 0) bsum[b] = red[0];
}

// ---------------- fused scan2+scan3 ----------------
__global__ void k_scan23(const int* __restrict__ deg, const int* __restrict__ bsum,
                         int* __restrict__ cursor) {
    __shared__ int sh[256];
    int b = blockIdx.x, t = threadIdx.x;
    sh[t] = (t < SCAN_B) ? bsum[t] : 0;
    __syncthreads();
    for (int o = 1; o < 256; o <<= 1) {
        int v = (t >= o) ? sh[t - o] : 0;
        __syncthreads();
        sh[t] += v;
        __syncthreads();
    }
    int boff = (b == 0) ? 0 : sh[b - 1];
    __syncthreads();
    int i = b * 256 + t;
    int v = (i < N_NODES) ? deg[i] : 0;
    sh[t] = v;
    __syncthreads();
    for (int o = 1; o < 256; o <<= 1) {
        int val = (t >= o) ? sh[t - o] : 0;
        __syncthreads();
        sh[t] += val;
        __syncthreads();
    }
    if (i < N_NODES) cursor[i] = boff + sh[t] - v;
}

// after this, cursor[i] == row END; start = cursor[i]-deg[i]
__global__ void k_bucket(const int* __restrict__ src, const int* __restrict__ dst,
                         int* __restrict__ cursor, int* __restrict__ csr_src) {
    int e = blockIdx.x * blockDim.x + threadIdx.x;
    if (e >= N_EDGES) return;
    int pos = atomicAdd(&cursor[dst[e]], 1);
    csr_src[pos] = src[e];
}

// ---------------- mean aggregation: fp8 gather, hi-only mean output ----------------
__global__ __launch_bounds__(256) void k_agg(const int* __restrict__ cursor,
                                             const int* __restrict__ deg,
                                             const int* __restrict__ csr,
                                             const unsigned char* __restrict__ Xf8,
                                             unsigned short* __restrict__ Ahi) {
    int node = blockIdx.x * 4 + (threadIdx.x >> 6);
    int lane = threadIdx.x & 63;
    if (node >= N_NODES) return;
    int d = deg[node], end = cursor[node], start = end - d;
    int h = lane >> 5;
    int col = (lane & 31) * 8;
    const unsigned char* Xb = Xf8 + col;
    float acc0[8] = {}, acc1[8] = {}, acc2[8] = {}, acc3[8] = {};
    int j = start;
    for (; j + 16 <= end; j += 16) {
        int i0 = csr[j + h],      i1 = csr[j + 2 + h],  i2 = csr[j + 4 + h],  i3 = csr[j + 6 + h];
        int i4 = csr[j + 8 + h],  i5 = csr[j + 10 + h], i6 = csr[j + 12 + h], i7 = csr[j + 14 + h];
        uint2 v0 = *(const uint2*)&Xb[(size_t)i0 * D];
        uint2 v1 = *(const uint2*)&Xb[(size_t)i1 * D];
        uint2 v2 = *(const uint2*)&Xb[(size_t)i2 * D];
        uint2 v3 = *(const uint2*)&Xb[(size_t)i3 * D];
        uint2 v4 = *(const uint2*)&Xb[(size_t)i4 * D];
        uint2 v5 = *(const uint2*)&Xb[(size_t)i5 * D];
        uint2 v6 = *(const uint2*)&Xb[(size_t)i6 * D];
        uint2 v7 = *(const uint2*)&Xb[(size_t)i7 * D];
        fp8x4_acc(v0.x, acc0); fp8x4_acc(v0.y, acc0 + 4);
        fp8x4_acc(v1.x, acc1); fp8x4_acc(v1.y, acc1 + 4);
        fp8x4_acc(v2.x, acc2); fp8x4_acc(v2.y, acc2 + 4);
        fp8x4_acc(v3.x, acc3); fp8x4_acc(v3.y, acc3 + 4);
        fp8x4_acc(v4.x, acc0); fp8x4_acc(v4.y, acc0 + 4);
        fp8x4_acc(v5.x, acc1); fp8x4_acc(v5.y, acc1 + 4);
        fp8x4_acc(v6.x, acc2); fp8x4_acc(v6.y, acc2 + 4);
        fp8x4_acc(v7.x, acc3); fp8x4_acc(v7.y, acc3 + 4);
    }
    if (j + 8 <= end) {
        int i0 = csr[j + h], i1 = csr[j + 2 + h], i2 = csr[j + 4 + h], i3 = csr[j + 6 + h];
        uint2 v0 = *(const uint2*)&Xb[(size_t)i0 * D];
        uint2 v1 = *(const uint2*)&Xb[(size_t)i1 * D];
        uint2 v2 = *(const uint2*)&Xb[(size_t)i2 * D];
        uint2 v3 = *(const uint2*)&Xb[(size_t)i3 * D];
        fp8x4_acc(v0.x, acc0); fp8x4_acc(v0.y, acc0 + 4);
        fp8x4_acc(v1.x, acc1); fp8x4_acc(v1.y, acc1 + 4);
        fp8x4_acc(v2.x, acc2); fp8x4_acc(v2.y, acc2 + 4);
        fp8x4_acc(v3.x, acc3); fp8x4_acc(v3.y, acc3 + 4);
        j += 8;
    }
    if (j + 4 <= end) {
        int i0 = csr[j + h], i1 = csr[j + 2 + h];
        uint2 v0 = *(const uint2*)&Xb[(size_t)i0 * D];
        uint2 v1 = *(const uint2*)&Xb[(size_t)i1 * D];
        fp8x4_acc(v0.x, acc0); fp8x4_acc(v0.y, acc0 + 4);
        fp8x4_acc(v1.x, acc1); fp8x4_acc(v1.y, acc1 + 4);
        j += 4;
    }
    if (j + 2 <= end) {
        int i0 = csr[j + h];
        uint2 v0 = *(const uint2*)&Xb[(size_t)i0 * D];
        fp8x4_acc(v0.x, acc0); fp8x4_acc(v0.y, acc0 + 4);
        j += 2;
    }
    if (j < end && h == 0) {
        int i0 = csr[j];
        uint2 v0 = *(const uint2*)&Xb[(size_t)i0 * D];
        fp8x4_acc(v0.x, acc0); fp8x4_acc(v0.y, acc0 + 4);
    }
    float inv = FP8_ACC_SCALE / fmaxf((float)d, 1.0f);
    ushort8 hi;
    #pragma unroll
    for (int k = 0; k < 8; k++) {
        float a = (acc0[k] + acc1[k]) + (acc2[k] + acc3[k]);
        a += __shfl_xor(a, 32);
        hi[k] = bf16_rn(a * inv);
    }
    if (h == 0) {
        *(ushort8*)&Ahi[(size_t)node * K2 + col] = hi;
    }
}

// ---------------- exact fp32 h1 rows for mention + its neighbors ----------------
__global__ __launch_bounds__(256) void k_small(const int* __restrict__ mention,
                                               const int* __restrict__ deg,
                                               const int* __restrict__ cursor,
                                               const int* __restrict__ csr,
                                               const float* __restrict__ x,
                                               const float* __restrict__ W1l,
                                               const float* __restrict__ W1r,
                                               const float* __restrict__ b1,
                                               float* __restrict__ h1m) {
    int m = mention[0];
    int dm = min(deg[m], 95);
    int slot = blockIdx.x;
    if (slot > dm) return;
    int startm = cursor[m] - deg[m];
    int node = (slot == 0) ? m : csr[startm + slot - 1];
    __shared__ float smean[D], sx[D];
    int t = threadIdx.x;
    int d = deg[node], end = cursor[node], start = end - d;
    float a = 0.f;
    for (int j = start; j < end; j++) a += x[(size_t)csr[j] * D + t];
    smean[t] = a / fmaxf((float)d, 1.0f);
    sx[t] = x[(size_t)node * D + t];
    __syncthreads();
    float z = b1[t];
    const float* wl = &W1l[(size_t)t * D];
    const float* wr = &W1r[(size_t)t * D];
    for (int k = 0; k < D; k += 4) {
        float4 a4 = *(const float4*)&wl[k];
        float4 b4 = *(const float4*)&wr[k];
        z += smean[k] * a4.x + smean[k + 1] * a4.y + smean[k + 2] * a4.z + smean[k + 3] * a4.w
           + sx[k] * b4.x + sx[k + 1] * b4.y + sx[k + 2] * b4.z + sx[k + 3] * b4.w;
    }
    h1m[(size_t)slot * D + t] = fmaxf(z, 0.f);
}

// ---------------- v = h2[mention]: 16 blocks x 16 rows, 16-lane dots ----------------
__global__ __launch_bounds__(256) void k_v(const int* __restrict__ mention,
                                           const int* __restrict__ deg,
                                           const float* __restrict__ h1m,
                                           const float* __restrict__ W2l,
                                           const float* __restrict__ W2r,
                                           const float* __restrict__ b2,
                                           float* __restrict__ v) {
    __shared__ float sm[D], sh[D];
    int m = mention[0];
    int dm = min(deg[m], 95);
    int t = threadIdx.x;
    float a = 0.f;
    for (int j = 1; j <= dm; j++) a += h1m[(size_t)j * D + t];
    sm[t] = a / fmaxf((float)deg[m], 1.0f);
    sh[t] = h1m[t];
    __syncthreads();
    int o = t >> 4, p = t & 15;
    int row = blockIdx.x * 16 + o;
    const float* wl = &W2l[(size_t)row * D];
    const float* wr = &W2r[(size_t)row * D];
    float acc = 0.f;
    int k0 = p * 16;
    #pragma unroll
    for (int k = k0; k < k0 + 16; k += 4) {
        float4 a4 = *(const float4*)&wl[k];
        float4 b4 = *(const float4*)&wr[k];
        acc += sm[k] * a4.x + sm[k + 1] * a4.y + sm[k + 2] * a4.z + sm[k + 3] * a4.w
             + sh[k] * b4.x + sh[k + 1] * b4.y + sh[k + 2] * b4.z + sh[k + 3] * b4.w;
    }
    #pragma unroll
    for (int off = 1; off < 16; off <<= 1) acc += __shfl_xor(acc, off);
    if (p == 0) v[row] = acc + b2[row];
}

// ---------------- u = [W2l^T v ; W2r^T v]; c = b2 . v ----------------
__global__ __launch_bounds__(256) void k_u(const float* __restrict__ W2l,
                                           const float* __restrict__ W2r,
                                           const float* __restrict__ b2,
                                           const float* __restrict__ v,
                                           float* __restrict__ u,
                                           float* __restrict__ cout) {
    __shared__ float sv[D];
    __shared__ float r1[4][64], r2[4][64], red[256];
    int t = threadIdx.x;
    sv[t] = v[t];
    __syncthreads();
    int lane = t & 63, p = t >> 6;
    int col = blockIdx.x * 64 + lane;
    float a1 = 0.f, a2 = 0.f;
    for (int n = p; n < D; n += 4) {
        float vv = sv[n];
        a1 += W2l[(size_t)n * D + col] * vv;
        a2 += W2r[(size_t)n * D + col] * vv;
    }
    r1[p][lane] = a1; r2[p][lane] = a2;
    __syncthreads();
    if (p == 0) {
        u[col] = r1[0][lane] + r1[1][lane] + r1[2][lane] + r1[3][lane];
        u[D + col] = r2[0][lane] + r2[1][lane] + r2[2][lane] + r2[3][lane];
    }
    if (blockIdx.x == 0) {
        red[t] = b2[t] * sv[t];
        __syncthreads();
        for (int o = 128; o; o >>= 1) {
            if (t < o) red[t] += red[t + o];
            __syncthreads();
        }
        if (t == 0) cout[0] = red[0];
    }
}

// ---------------- fused split-bf16 MFMA GEMM + relu + projection epilogue ----------------
// R11's measured-best shape: BM=64 x BN=256, 4 waves; phase 1 (mean) hi*hi;
// phase 2 (x half) 3-term Ahi*Bhi + Ahi*Blo + Alo*Bhi. 52.8 us / WRITE 0.39 MB (R11).
__global__ __launch_bounds__(256, 4)
void k_gemm_fused(const unsigned short* __restrict__ Ahi,
                  const unsigned short* __restrict__ Alo,
                  const unsigned short* __restrict__ Bhi,
                  const unsigned short* __restrict__ Blo,
                  const float* __restrict__ bias,
                  const float* __restrict__ u,    // u1[256] then u2[256]
                  float* __restrict__ s,
                  float* __restrict__ t_) {
    __shared__ unsigned short sA[2][BM * BK];   // 8 KB
    __shared__ unsigned short sB[2][BN * BK];   // 32 KB
    __shared__ float sred[BM], tred[BM];
    int tid = threadIdx.x;
    int br = blockIdx.x;
    int lane = tid & 63, wv = tid >> 6;          // 4 waves
    int wn = wv * 64;
    int q = lane >> 4, r = lane & 15;

    float biasv[4], u1v[4], u2v[4];
    #pragma unroll
    for (int nt = 0; nt < 4; nt++) {
        int gc = wn + nt * 16 + r;
        biasv[nt] = bias[gc];
        u1v[nt] = u[gc];
        u2v[nt] = u[256 + gc];
    }
    if (tid < BM) { sred[tid] = 0.f; tred[tid] = 0.f; }

    floatx4 acc[4][4] = {};

    const size_t arow0 = (size_t)br * BM;
    int seg = lane & 3;
    int rl16 = lane >> 2;

    // ---- phase 1: kt 0..7 (mean half), hi*hi ----
    for (int kt = 0; kt < 8; kt++) {
        {
            size_t gA = (arow0 + wv * 16 + rl16) * (size_t)K2 + kt * BK + seg * 8;
            load_lds16(Ahi + gA, &sA[0][(wv * 16) * BK]);
        }
        #pragma unroll
        for (int t = 0; t < 4; t++) {
            int rloc = wv * 64 + t * 16 + rl16;
            size_t gB = (size_t)rloc * K2 + kt * BK + seg * 8;
            load_lds16(Bhi + gB, &sB[0][(wv * 64 + t * 16) * BK]);
        }
        __syncthreads();
        short8 ah[4], bh[4];
        #pragma unroll
        for (int i = 0; i < 4; i++) {
            ah[i] = *(const short8*)&sA[0][(i * 16 + r) * BK + q * 8];
            bh[i] = *(const short8*)&sB[0][(wn + i * 16 + r) * BK + q * 8];
        }
        #pragma unroll
        for (int mt = 0; mt < 4; mt++)
            #pragma unroll
            for (int nt = 0; nt < 4; nt++)
                acc[mt][nt] = __builtin_amdgcn_mfma_f32_16x16x32_bf16(ah[mt], bh[nt], acc[mt][nt], 0, 0, 0);
        __syncthreads();
    }

    // ---- phase 2: kt 8..15 (x half), 3-term split ----
    for (int kt = 8; kt < 16; kt++) {
        {
            size_t gA = (arow0 + wv * 16 + rl16) * (size_t)K2 + kt * BK + seg * 8;
            load_lds16(Ahi + gA, &sA[0][(wv * 16) * BK]);
            load_lds16(Alo + gA, &sA[1][(wv * 16) * BK]);
        }
        #pragma unroll
        for (int t = 0; t < 4; t++) {
            int rloc = wv * 64 + t * 16 + rl16;
            size_t gB = (size_t)rloc * K2 + kt * BK + seg * 8;
            load_lds16(Bhi + gB, &sB[0][(wv * 64 + t * 16) * BK]);
            load_lds16(Blo + gB, &sB[1][(wv * 64 + t * 16) * BK]);
        }
        __syncthreads();
        short8 ah[4], al[4], bh[4], bl[4];
        #pragma unroll
        for (int i = 0; i < 4; i++) {
            ah[i] = *(const short8*)&sA[0][(i * 16 + r) * BK + q * 8];
            al[i] = *(const short8*)&sA[1][(i * 16 + r) * BK + q * 8];
            bh[i] = *(const short8*)&sB[0][(wn + i * 16 + r) * BK + q * 8];
            bl[i] = *(const short8*)&sB[1][(wn + i * 16 + r) * BK + q * 8];
        }
        #pragma unroll
        for (int mt = 0; mt < 4; mt++)
            #pragma unroll
            for (int nt = 0; nt < 4; nt++) {
                acc[mt][nt] = __builtin_amdgcn_mfma_f32_16x16x32_bf16(ah[mt], bh[nt], acc[mt][nt], 0, 0, 0);
                acc[mt][nt] = __builtin_amdgcn_mfma_f32_16x16x32_bf16(ah[mt], bl[nt], acc[mt][nt], 0, 0, 0);
                acc[mt][nt] = __builtin_amdgcn_mfma_f32_16x16x32_bf16(al[mt], bh[nt], acc[mt][nt], 0, 0, 0);
            }
        __syncthreads();
    }

    #pragma unroll
    for (int mt = 0; mt < 4; mt++) {
        #pragma unroll
        for (int reg = 0; reg < 4; reg++) {
            float sacc = 0.f, tacc = 0.f;
            #pragma unroll
            for (int nt = 0; nt < 4; nt++) {
                float h = fmaxf(acc[mt][nt][reg] + biasv[nt], 0.f);
                sacc += h * u1v[nt];
                tacc += h * u2v[nt];
            }
            #pragma unroll
            for (int off = 1; off < 16; off <<= 1) {
                sacc += __shfl_xor(sacc, off);
                tacc += __shfl_xor(tacc, off);
            }
            if (r == 0) {
                int row = mt * 16 + q * 4 + reg;
                atomicAdd(&sred[row], sacc);
                atomicAdd(&tred[row], tacc);
            }
        }
    }
    __syncthreads();
    if (tid < BM) {
        size_t grow = arow0 + tid;
        if (grow < N_NODES) {
            s[grow] = sred[tid];
            t_[grow] = tred[tid];
        }
    }
}

// ---------------- fused logits + per-block softmax partials ----------------
__global__ __launch_bounds__(256) void k_logits_sm1(const int* __restrict__ deg,
                                                    const int* __restrict__ cursor,
                                                    const int* __restrict__ csr,
                                                    const float* __restrict__ s,
                                                    const float* __restrict__ t_,
                                                    const float* __restrict__ cptr,
                                                    float* __restrict__ logits,
                                                    float* __restrict__ pmax,
                                                    float* __restrict__ psum) {
    __shared__ float red[256];
    int b = blockIdx.x, t = threadIdx.x;
    int i = b * 256 + t;
    float lg = -INFINITY;
    if (i < N_NODES) {
        int d = deg[i];
        int end = cursor[i];
        int j = end - d;
        float sum = 0.f;
        for (; j + 4 <= end; j += 4) {     // 4 independent gathers in flight
            int i0 = csr[j], i1 = csr[j + 1], i2 = csr[j + 2], i3 = csr[j + 3];
            sum += (s[i0] + s[i1]) + (s[i2] + s[i3]);
        }
        for (; j < end; j++) sum += s[csr[j]];
        lg = sum / fmaxf((float)d, 1.0f) + t_[i] + cptr[0];
        logits[i] = lg;
    }
    red[t] = lg;
    __syncthreads();
    for (int o = 128; o; o >>= 1) {
        if (t < o) red[t] = fmaxf(red[t], red[t + o]);
        __syncthreads();
    }
    float mb = red[0];
    __syncthreads();
    red[t] = (i < N_NODES) ? __expf(lg - mb) : 0.f;
    __syncthreads();
    for (int o = 128; o; o >>= 1) {
        if (t < o) red[t] += red[t + o];
        __syncthreads();
    }
    if (t == 0) { pmax[b] = mb; psum[b] = red[0]; }
}

// ---------------- fused sm2+sm3: redundant partial-reduce + finalize ----------------
__global__ __launch_bounds__(256) void k_sm23(const float* __restrict__ logits,
                                              const float* __restrict__ pmax,
                                              const float* __restrict__ psum,
                                              float* __restrict__ out) {
    __shared__ float rm[256], rs[256];
    int b = blockIdx.x, t = threadIdx.x;
    float m = (t < SCAN_B) ? pmax[t] : -INFINITY;
    rm[t] = m;
    __syncthreads();
    for (int o = 128; o; o >>= 1) {
        if (t < o) rm[t] = fmaxf(rm[t], rm[t + o]);
        __syncthreads();
    }
    float g = rm[0];
    __syncthreads();
    rs[t] = (t < SCAN_B) ? psum[t] * __expf(m - g) : 0.f;
    __syncthreads();
    for (int o = 128; o; o >>= 1) {
        if (t < o) rs[t] += rs[t + o];
        __syncthreads();
    }
    float inv = 1.0f / rs[0];
    int i = b * 256 + t;
    if (i < N_NODES) out[i] = __expf(logits[i] - g) * inv;
}

extern "C" void kernel_launch(void* const* d_in, const int* in_sizes, int n_in,
                              void* d_out, int out_size, void* d_ws, size_t ws_size,
                              hipStream_t stream) {
    const float* x   = (const float*)d_in[0];
    const int*   ei  = (const int*)d_in[1];
    const int*   src = ei;
    const int*   dst = ei + N_EDGES;
    const int*   mention = (const int*)d_in[2];
    const float* W1l = (const float*)d_in[3];
    const float* b1  = (const float*)d_in[4];
    const float* W1r = (const float*)d_in[5];
    const float* W2l = (const float*)d_in[6];
    const float* b2  = (const float*)d_in[7];
    const float* W2r = (const float*)d_in[8];

    char* w = (char*)d_ws;
    unsigned short* Ahi = (unsigned short*)w;  w += (size_t)M_PAD * K2 * 2;
    unsigned short* Alo = (unsigned short*)w;  w += (size_t)M_PAD * K2 * 2;
    unsigned short* Bhi = (unsigned short*)w;  w += (size_t)256 * K2 * 2;
    unsigned short* Blo = (unsigned short*)w;  w += (size_t)256 * K2 * 2;
    unsigned char* Xf8 = (unsigned char*)w;    w += (size_t)N_NODES * D;
    float* s     = (float*)w;  w += (size_t)N_NODES * 4;
    float* t_    = (float*)w;  w += (size_t)N_NODES * 4;
    int* deg     = (int*)w;    w += (size_t)N_NODES * 4;   // zeroed
    float* logit = (float*)w;  w += (size_t)N_NODES * 4;
    float* h1m   = (float*)w;  w += (size_t)96 * D * 4;
    float* vbuf  = (float*)w;  w += D * 4;
    float* u     = (float*)w;  w += 2 * D * 4;
    float* c     = (float*)w;  w += 16;
    float* pmax  = (float*)w;  w += 256 * 4;
    float* psum  = (float*)w;  w += 256 * 4;
    int* cursor  = (int*)w;    w += (size_t)N_NODES * 4;
    int* bsum    = (int*)w;    w += 256 * 4;
    int* csr     = (int*)w;    w += (size_t)N_EDGES * 4;

    hipMemsetAsync(deg, 0, (size_t)N_NODES * sizeof(int), stream);

    k_init  <<<SPX_B + SPB_B + CNT_B, 256, 0, stream>>>(x, W1l, W1r, dst,
                                                        Ahi, Alo, Bhi, Blo, Xf8, deg);
    k_scan1 <<<SCAN_B, 256, 0, stream>>>(deg, bsum);
    k_scan23<<<SCAN_B, 256, 0, stream>>>(deg, bsum, cursor);
    k_bucket<<<(N_EDGES + 255) / 256, 256, 0, stream>>>(src, dst, cursor, csr);

    k_agg   <<<(N_NODES + 3) / 4, 256, 0, stream>>>(cursor, deg, csr, Xf8, Ahi);

    k_small <<<96, 256, 0, stream>>>(mention, deg, cursor, csr, x, W1l, W1r, b1, h1m);
    k_v     <<<16, 256, 0, stream>>>(mention, deg, h1m, W2l, W2r, b2, vbuf);
    k_u     <<<4, 256, 0, stream>>>(W2l, W2r, b2, vbuf, u, c);

    k_gemm_fused<<<M_PAD / BM, 256, 0, stream>>>(Ahi, Alo, Bhi, Blo, b1, u, s, t_);

    k_logits_sm1<<<SCAN_B, 256, 0, stream>>>(deg, cursor, csr, s, t_, c, logit, pmax, psum);
    k_sm23  <<<SCAN_B, 256, 0, stream>>>(logit, pmax, psum, (float*)d_out);
}